// Round 21
// baseline (65.344 us; speedup 1.0000x reference)
//
#include <hip/hip_runtime.h>
#include <hip/hip_bf16.h>

#define B_GR   16
#define N_PER  1024
#define M_PER  4096
#define NVEC   64
#define FDIM   192      // 3*NVEC
#define FSKIP  64
#define HID    256
#define ODIM   128
#define N_TOT  (B_GR * N_PER)   // 16384
#define M_TOT  (B_GR * M_PER)   // 65536

typedef __attribute__((ext_vector_type(8))) short short8v;   // 8 bf16 = 4 VGPR
typedef __attribute__((ext_vector_type(4))) float f32x4;     // MFMA acc

__device__ __forceinline__ unsigned short f2bf(float f) {
    __hip_bfloat16 h = __float2bfloat16(f);   // RNE
    return *reinterpret_cast<unsigned short*>(&h);
}

// swizzled element index into a [64][256] bf16 row-major LDS tile.
__device__ __forceinline__ int hsw(int r, int e) {
    return r * 256 + (e ^ ((r & 7) << 3));
}

// ---------------------------------------------------------------------------
// Kernel 0: weight prep only (384 blocks; tail copy moved into fused_kernel).
// ---------------------------------------------------------------------------
__global__ __launch_bounds__(256) void wprep_kernel(
    const float* __restrict__ W1, const float* __restrict__ W2,
    unsigned short* __restrict__ wt1, unsigned short* __restrict__ wt2)
{
    const int i = blockIdx.x * 256 + threadIdx.x;
    if (i < 65536) {                          // W1: 256x256
        const int k = i >> 8, c = i & 255;
        wt1[c * 256 + k] = f2bf(W1[i]);
    } else {                                  // W2: 256x128
        const int j = i - 65536;
        const int k = j >> 7, c = j & 127;
        wt2[c * 256 + k] = f2bf(W2[j]);
    }
}

// ---------------------------------------------------------------------------
// Kernel 1: fully fused KNN + edge-transform + MFMA MLP + tuple tail.
// r21 = r20 champion (64.8us) hot path VERBATIM + tail copy absorbed at the
// end of each block (832 elements x 1024 blocks = 851968 exactly) — kills
// the 3712-block prep_tail dispatch (~5us serialized stream time).
// EVIDENCE LOG: r6/r7 spill 394/194us | r8 fat scan 157us | r10 bundle
// 101us | r13 dual-acc null | r14 global-scan 83.5us | r15 2-query scan
// broken (retired) | r17 register diet failed | r18 half-block 82us | r19
// split 78.8us (isolated 50us latency-bound mlp) | r20 MLP prefetch +
// phase-A gather batching: 66.3 -> 64.8us (VGPR 36 held).
// REGISTER RULE (r10): 36 VGPR + 32 AGPR = 68 unified; (512,2) caps 128.
// ---------------------------------------------------------------------------
__global__ __launch_bounds__(512, 2) void fused_kernel(
    const float* __restrict__ x,             // [N_TOT,192]
    const float* __restrict__ pos,           // [N_TOT,3]
    const float* __restrict__ pos_skip,      // [M_TOT,3]
    const float* __restrict__ x_skip,        // [M_TOT,64]
    const float* __restrict__ lframes,       // [N_TOT,3,3]
    const float* __restrict__ lframes_skip,  // [M_TOT,3,3]
    const unsigned short* __restrict__ wt1,  // [256][256] bf16 (c-major)
    const float* __restrict__ b1,            // [256]
    const unsigned short* __restrict__ wt2,  // [128][256] bf16 (c-major)
    const float* __restrict__ b2,            // [128]
    const int*   __restrict__ batch_skip,    // [M_TOT] int32
    float* __restrict__ out)                 // [M_TOT,128] then tail
{
    __shared__ __align__(16) char smraw[64 * 256 * 2];   // 32 KB: pc ∪ hb
    __shared__ __align__(16) float Usc[64 * 28];         // 7 KB scaled-U
    __shared__ int idxL[64 * 3];                         // LOCAL nbr indices

    float4*         pc = reinterpret_cast<float4*>(smraw);          // [1024]
    unsigned short* hb = reinterpret_cast<unsigned short*>(smraw);  // [64*256]

    const int tid  = threadIdx.x;
    const int lane = tid & 63;
    const int wv   = tid >> 6;               // 0..7
    const int raw  = blockIdx.x;
    const int blk  = (raw & 7) * 128 + (raw >> 3);   // XCD-contiguous batches
    const int lo   = lane & 15;
    const int hi   = lane >> 4;
    const int b    = blk >> 6;               // 64 blocks per batch

    // ---------------- Phase K: candidate cache + top-3 scan ----------------
    #pragma unroll
    for (int k = 0; k < 2; ++k) {
        const int j = tid + k * 512;
        const float* p = pos + (size_t)(b * N_PER + j) * 3;
        float a0 = p[0], a1 = p[1], a2 = p[2];
        pc[j] = make_float4(a0, a1, a2, a0*a0 + a1*a1 + a2*a2);
    }
    __syncthreads();

    {
        const int q   = tid >> 3;            // query row 0..63
        const int sub = tid & 7;
        const int m   = blk * 64 + q;
        float nqx, nqy, nqz, qq;
        {
            const float qx = pos_skip[m*3+0], qy = pos_skip[m*3+1],
                        qz = pos_skip[m*3+2];
            qq  = qx*qx + qy*qy + qz*qz;
            nqx = -2.0f*qx; nqy = -2.0f*qy; nqz = -2.0f*qz;
        }

        float d0 = 1e30f, d1 = 1e30f, d2 = 1e30f;
        int   i0 = 0,     i1 = 0,     i2 = 0;
        #pragma unroll 4
        for (int t = 0; t < 128; ++t) {
            const int j = t*8 + sub;         // wave reads 128B bcast x8
            float4 c = pc[j];
            float r = fmaf(nqx, c.x, fmaf(nqy, c.y, fmaf(nqz, c.z, qq + c.w)));
            bool c0 = r < d0, c1 = r < d1, c2 = r < d2;
            i2 = c2 ? (c1 ? i1 : j) : i2;
            i1 = c1 ? (c0 ? i0 : j) : i1;
            i0 = c0 ? j : i0;
            d2 = c2 ? (c1 ? d1 : r) : d2;
            d1 = c1 ? (c0 ? d0 : r) : d1;
            d0 = c0 ? r : d0;
        }
        // 3-level butterfly merge across the 8 sublanes, lexicographic (d, j)
        #pragma unroll
        for (int mask = 1; mask <= 4; mask <<= 1) {
            float e0 = __shfl_xor(d0, mask), e1 = __shfl_xor(d1, mask),
                  e2 = __shfl_xor(d2, mask);
            int   j0 = __shfl_xor(i0, mask), j1 = __shfl_xor(i1, mask),
                  j2 = __shfl_xor(i2, mask);
            const float ee[3] = {e0, e1, e2};
            const int   jj[3] = {j0, j1, j2};
            #pragma unroll
            for (int s = 0; s < 3; ++s) {
                const float e = ee[s]; const int j = jj[s];
                bool c0 = (e < d0) || (e == d0 && j < i0);
                bool c1 = (e < d1) || (e == d1 && j < i1);
                bool c2 = (e < d2) || (e == d2 && j < i2);
                i2 = c2 ? (c1 ? i1 : j) : i2;
                i1 = c1 ? (c0 ? i0 : j) : i1;
                i0 = c0 ? j : i0;
                d2 = c2 ? (c1 ? d1 : e) : d2;
                d1 = c1 ? (c0 ? d0 : e) : d1;
                d0 = c0 ? e : d0;
            }
        }

        // -------- fused phase U: all 8 sublanes hold the merged top-3 -------
        if (sub < 3) {
            const int jl = (sub == 0) ? i0 : (sub == 1) ? i1 : i2;
            idxL[q*3 + sub] = jl;            // local index, for phase A

            const float qx = -0.5f*nqx, qy = -0.5f*nqy, qz = -0.5f*nqz;
            float w[3];
            const int jls[3] = {i0, i1, i2};
            #pragma unroll
            for (int s = 0; s < 3; ++s) {
                float4 c = pc[jls[s]];
                float dx = c.x - qx, dy = c.y - qy, dz = c.z - qz;
                w[s] = 1.0f / fmaxf(dx*dx + dy*dy + dz*dz, 1e-16f);
            }
            const float wsub = (sub == 0) ? w[0] : (sub == 1) ? w[1] : w[2];
            const float sS   = wsub / (w[0] + w[1] + w[2]);
            const int   nb   = b * N_PER + jl;

            float RyS[9], Rx[9];
            #pragma unroll
            for (int t = 0; t < 9; ++t) RyS[t] = sS * lframes_skip[(size_t)m*9 + t];
            #pragma unroll
            for (int t = 0; t < 9; ++t) Rx[t] = lframes[(size_t)nb*9 + t];

            float* dst = &Usc[q*28 + sub*9];
            #pragma unroll
            for (int a = 0; a < 3; ++a)
                #pragma unroll
                for (int c = 0; c < 3; ++c)
                    dst[a*3+c] = RyS[a*3+0]*Rx[c*3+0]
                               + RyS[a*3+1]*Rx[c*3+1]
                               + RyS[a*3+2]*Rx[c*3+2];
        }
    }

    // early x_skip staging for rows 32-63 (hb rows >=32 never alias pc)
    if (wv >= 4) {
        #pragma unroll
        for (int rr = 0; rr < 8; ++rr) {
            const int r = wv * 8 + rr;       // 32..63
            const int m = blk * 64 + r;
            hb[hsw(r, 192+lane)] = f2bf(x_skip[(size_t)m*FSKIP + lane]);
        }
    }
    __syncthreads();   // idxL + Usc visible; pc reads done before hb overwrite

    // ---------------- Phase A: build h (bf16), row-PAIR pipelined ----------
    for (int rr = 0; rr < 8; rr += 2) {
        const int r0 = wv * 8 + rr;
        const int r1 = r0 + 1;
        const int m0 = blk * 64 + r0;
        const int m1 = blk * 64 + r1;
        const int nbs0[3] = {b*N_PER + idxL[r0*3+0],
                             b*N_PER + idxL[r0*3+1],
                             b*N_PER + idxL[r0*3+2]};
        const int nbs1[3] = {b*N_PER + idxL[r1*3+0],
                             b*N_PER + idxL[r1*3+1],
                             b*N_PER + idxL[r1*3+2]};

        // issue ALL global gathers for both rows before any math
        float v0[3][3], v1[3][3];
        #pragma unroll
        for (int k = 0; k < 3; ++k) {
            const float* xp = x + (size_t)nbs0[k]*FDIM + lane*3;
            v0[k][0] = xp[0]; v0[k][1] = xp[1]; v0[k][2] = xp[2];
        }
        #pragma unroll
        for (int k = 0; k < 3; ++k) {
            const float* xp = x + (size_t)nbs1[k]*FDIM + lane*3;
            v1[k][0] = xp[0]; v1[k][1] = xp[1]; v1[k][2] = xp[2];
        }
        float xs0 = 0.f, xs1 = 0.f;
        if (wv < 4) {
            xs0 = x_skip[(size_t)m0*FSKIP + lane];
            xs1 = x_skip[(size_t)m1*FSKIP + lane];
        }

        // row 0: U (LDS broadcast) + FMA + write
        {
            float Ub[28];
            float4* Ub4 = reinterpret_cast<float4*>(Ub);
            #pragma unroll
            for (int t = 0; t < 7; ++t)
                Ub4[t] = *reinterpret_cast<const float4*>(&Usc[r0*28 + t*4]);
            float n0 = 0.f, n1 = 0.f, n2 = 0.f;
            #pragma unroll
            for (int k = 0; k < 3; ++k) {
                const int o = k*9;
                n0 += Ub[o+0]*v0[k][0] + Ub[o+1]*v0[k][1] + Ub[o+2]*v0[k][2];
                n1 += Ub[o+3]*v0[k][0] + Ub[o+4]*v0[k][1] + Ub[o+5]*v0[k][2];
                n2 += Ub[o+6]*v0[k][0] + Ub[o+7]*v0[k][1] + Ub[o+8]*v0[k][2];
            }
            hb[hsw(r0, lane*3+0)] = f2bf(n0);
            hb[hsw(r0, lane*3+1)] = f2bf(n1);
            hb[hsw(r0, lane*3+2)] = f2bf(n2);
            if (wv < 4) hb[hsw(r0, 192+lane)] = f2bf(xs0);
        }
        // row 1
        {
            float Ub[28];
            float4* Ub4 = reinterpret_cast<float4*>(Ub);
            #pragma unroll
            for (int t = 0; t < 7; ++t)
                Ub4[t] = *reinterpret_cast<const float4*>(&Usc[r1*28 + t*4]);
            float n0 = 0.f, n1 = 0.f, n2 = 0.f;
            #pragma unroll
            for (int k = 0; k < 3; ++k) {
                const int o = k*9;
                n0 += Ub[o+0]*v1[k][0] + Ub[o+1]*v1[k][1] + Ub[o+2]*v1[k][2];
                n1 += Ub[o+3]*v1[k][0] + Ub[o+4]*v1[k][1] + Ub[o+5]*v1[k][2];
                n2 += Ub[o+6]*v1[k][0] + Ub[o+7]*v1[k][1] + Ub[o+8]*v1[k][2];
            }
            hb[hsw(r1, lane*3+0)] = f2bf(n0);
            hb[hsw(r1, lane*3+1)] = f2bf(n1);
            hb[hsw(r1, lane*3+2)] = f2bf(n2);
            if (wv < 4) hb[hsw(r1, 192+lane)] = f2bf(xs1);
        }
    }
    __syncthreads();

    // ---------------- GEMM1: hidden = relu(h @ W1 + b1) ----------------
    // wave wv covers cols [wv*32, wv*32+32); B-frags prefetched 1 K-step ahead
    f32x4 acc[4][2];
    #pragma unroll
    for (int fi = 0; fi < 4; ++fi)
        #pragma unroll
        for (int ci = 0; ci < 2; ++ci) acc[fi][ci] = (f32x4)0.f;

    short8v bfn[2];
    #pragma unroll
    for (int ci = 0; ci < 2; ++ci)
        bfn[ci] = *reinterpret_cast<const short8v*>(
            &wt1[(wv*32 + ci*16 + lo)*256 + hi*8]);

    for (int ks = 0; ks < 8; ++ks) {
        const int kk = ks*32 + hi*8;
        short8v bf0 = bfn[0], bf1 = bfn[1];
        if (ks < 7) {
            #pragma unroll
            for (int ci = 0; ci < 2; ++ci)
                bfn[ci] = *reinterpret_cast<const short8v*>(
                    &wt1[(wv*32 + ci*16 + lo)*256 + kk + 32]);
        }
        short8v a[4];
        #pragma unroll
        for (int fi = 0; fi < 4; ++fi) {
            const int r = fi*16 + lo;
            a[fi] = *reinterpret_cast<const short8v*>(
                &hb[r*256 + (kk ^ ((lo & 7) << 3))]);
        }
        #pragma unroll
        for (int fi = 0; fi < 4; ++fi) {
            acc[fi][0] = __builtin_amdgcn_mfma_f32_16x16x32_bf16(
                a[fi], bf0, acc[fi][0], 0, 0, 0);
            acc[fi][1] = __builtin_amdgcn_mfma_f32_16x16x32_bf16(
                a[fi], bf1, acc[fi][1], 0, 0, 0);
        }
    }
    __syncthreads();   // all GEMM1 reads of h complete

    {
        float b1v[2];
        #pragma unroll
        for (int ci = 0; ci < 2; ++ci) b1v[ci] = b1[wv*32 + ci*16 + lo];
        #pragma unroll
        for (int fi = 0; fi < 4; ++fi)
            #pragma unroll
            for (int ci = 0; ci < 2; ++ci)
                #pragma unroll
                for (int q = 0; q < 4; ++q) {
                    const int r = fi*16 + hi*4 + q;
                    const int c = wv*32 + ci*16 + lo;
                    hb[hsw(r, c)] = f2bf(fmaxf(acc[fi][ci][q] + b1v[ci], 0.f));
                }
    }
    __syncthreads();

    // ---------------- GEMM2: out = hidden @ W2 + b2 ----------------
    // wave wv covers cols [wv*16, wv*16+16); B-frag prefetched 1 K-step ahead
    f32x4 acc2[4];
    #pragma unroll
    for (int fi = 0; fi < 4; ++fi) acc2[fi] = (f32x4)0.f;

    short8v bf2n = *reinterpret_cast<const short8v*>(
        &wt2[(wv*16 + lo)*256 + hi*8]);

    for (int ks = 0; ks < 8; ++ks) {
        const int kk = ks*32 + hi*8;
        short8v bf = bf2n;
        if (ks < 7)
            bf2n = *reinterpret_cast<const short8v*>(
                &wt2[(wv*16 + lo)*256 + kk + 32]);
        short8v a[4];
        #pragma unroll
        for (int fi = 0; fi < 4; ++fi) {
            const int r = fi*16 + lo;
            a[fi] = *reinterpret_cast<const short8v*>(
                &hb[r*256 + (kk ^ ((lo & 7) << 3))]);
        }
        #pragma unroll
        for (int fi = 0; fi < 4; ++fi)
            acc2[fi] = __builtin_amdgcn_mfma_f32_16x16x32_bf16(
                a[fi], bf, acc2[fi], 0, 0, 0);
    }

    {
        const float b2v = b2[wv*16 + lo];
        #pragma unroll
        for (int fi = 0; fi < 4; ++fi)
            #pragma unroll
            for (int q = 0; q < 4; ++q) {
                const int r = fi*16 + hi*4 + q;
                const int c = wv*16 + lo;
                out[(size_t)(blk*64 + r)*ODIM + c] = acc2[fi][q] + b2v;
            }
    }

    // ---------------- Tail copy: 832 elements per block (exact) ------------
    {
        float* tail = out + (size_t)M_TOT * ODIM;
        const int P = M_TOT * 3;
        const int Q = P + M_TOT;
        const int base = raw * 832;          // 1024 blocks x 832 = 851968
        #pragma unroll
        for (int i = tid; i < 832; i += 512) {
            const int t = base + i;
            float v;
            if (t < P)      v = pos_skip[t];
            else if (t < Q) v = (float)batch_skip[t - P];
            else            v = lframes_skip[t - Q];
            tail[t] = v;
        }
    }
}

extern "C" void kernel_launch(void* const* d_in, const int* in_sizes, int n_in,
                              void* d_out, int out_size, void* d_ws, size_t ws_size,
                              hipStream_t stream) {
    const float* x            = (const float*)d_in[0];
    const float* pos          = (const float*)d_in[1];
    const float* pos_skip     = (const float*)d_in[2];
    const float* x_skip       = (const float*)d_in[3];
    const float* lframes      = (const float*)d_in[4];
    const float* lframes_skip = (const float*)d_in[5];
    const float* W1           = (const float*)d_in[6];
    const float* b1           = (const float*)d_in[7];
    const float* W2           = (const float*)d_in[8];
    const float* b2           = (const float*)d_in[9];
    const int*   batch_skip   = (const int*)d_in[11];

    char* ws = (char*)d_ws;
    unsigned short* wt1 = (unsigned short*)ws;                 // 131072 B
    unsigned short* wt2 = (unsigned short*)(ws + 131072);      // 65536 B
    float* out = (float*)d_out;

    // weight prep only: 98304 threads = 384 blocks
    wprep_kernel<<<384, 256, 0, stream>>>(W1, W2, wt1, wt2);

    fused_kernel<<<M_TOT/64, 512, 0, stream>>>(x, pos, pos_skip, x_skip,
                                               lframes, lframes_skip,
                                               wt1, b1, wt2, b2,
                                               batch_skip, out);
}

// Round 22
// 64.395 us; speedup vs baseline: 1.0147x; 1.0147x over previous
//
#include <hip/hip_runtime.h>
#include <hip/hip_bf16.h>

#define B_GR   16
#define N_PER  1024
#define M_PER  4096
#define NVEC   64
#define FDIM   192      // 3*NVEC
#define FSKIP  64
#define HID    256
#define ODIM   128
#define N_TOT  (B_GR * N_PER)   // 16384
#define M_TOT  (B_GR * M_PER)   // 65536

typedef __attribute__((ext_vector_type(8))) short short8v;   // 8 bf16 = 4 VGPR
typedef __attribute__((ext_vector_type(4))) float f32x4;     // MFMA acc

__device__ __forceinline__ unsigned short f2bf(float f) {
    __hip_bfloat16 h = __float2bfloat16(f);   // RNE
    return *reinterpret_cast<unsigned short*>(&h);
}

// swizzled element index into a [64][256] bf16 row-major LDS tile.
__device__ __forceinline__ int hsw(int r, int e) {
    return r * 256 + (e ^ ((r & 7) << 3));
}

// ---------------------------------------------------------------------------
// Kernel 0: merged prep + tail (r16 proven; r21 showed absorbing the tail
// into fused_kernel is net-neutral/negative — separate small dispatch wins).
// ---------------------------------------------------------------------------
__global__ __launch_bounds__(256) void prep_tail_kernel(
    const float* __restrict__ W1, const float* __restrict__ W2,
    const float* __restrict__ pos_skip,
    const int*   __restrict__ batch_skip,
    const float* __restrict__ lframes_skip,
    unsigned short* __restrict__ wt1, unsigned short* __restrict__ wt2,
    float* __restrict__ dst)
{
    const int i = blockIdx.x * 256 + threadIdx.x;
    if (i < 65536) {                          // W1: 256x256
        const int k = i >> 8, c = i & 255;
        wt1[c * 256 + k] = f2bf(W1[i]);
    } else if (i < 98304) {                   // W2: 256x128
        const int j = i - 65536;
        const int k = j >> 7, c = j & 127;
        wt2[c * 256 + k] = f2bf(W2[j]);
    } else {                                  // tail: 851968 elements
        const int t = i - 98304;
        const int P = M_TOT * 3;
        const int Q = P + M_TOT;
        if (t < P)      dst[t] = pos_skip[t];
        else if (t < Q) dst[t] = (float)batch_skip[t - P];
        else            dst[t] = lframes_skip[t - Q];
    }
}

// ---------------------------------------------------------------------------
// Kernel 1: fully fused KNN + edge-transform + MFMA MLP.
// == r20 CHAMPION VERBATIM (64.8 us total, VGPR 36, best of 21 rounds) ==
//  - 8-sublane-per-query scan (LDS-pipe floor ~20us), fmaf ranking,
//    3-level shfl_xor lexicographic butterfly (exact lax.top_k tie rule)
//  - phase U fused into scan tail; XCD swizzle (FETCH 52->17MB)
//  - phase A row-pair gather batching; GEMM1/2 1-deep B-frag prefetch
// FINAL EVIDENCE LOG: r6/r7 spill 394/194us | r8 fat scan 157us | r10
// bundle 101us | r13 dual-acc null | r14 global-scan 83.5us | r15 2-query
// scan broken | r17 register diet failed | r18 half-block 82us | r19 split
// 78.8us | r20 MLP prefetch 64.8us (champion) | r21 tail absorption 65.3us
// (reverted). Remaining stall = phase-serialization at 2 blocks/CU; no pipe
// saturated; all structural levers exhausted -> practical floor.
// ---------------------------------------------------------------------------
__global__ __launch_bounds__(512, 2) void fused_kernel(
    const float* __restrict__ x,             // [N_TOT,192]
    const float* __restrict__ pos,           // [N_TOT,3]
    const float* __restrict__ pos_skip,      // [M_TOT,3]
    const float* __restrict__ x_skip,        // [M_TOT,64]
    const float* __restrict__ lframes,       // [N_TOT,3,3]
    const float* __restrict__ lframes_skip,  // [M_TOT,3,3]
    const unsigned short* __restrict__ wt1,  // [256][256] bf16 (c-major)
    const float* __restrict__ b1,            // [256]
    const unsigned short* __restrict__ wt2,  // [128][256] bf16 (c-major)
    const float* __restrict__ b2,            // [128]
    float* __restrict__ out)                 // [M_TOT,128]
{
    __shared__ __align__(16) char smraw[64 * 256 * 2];   // 32 KB: pc ∪ hb
    __shared__ __align__(16) float Usc[64 * 28];         // 7 KB scaled-U
    __shared__ int idxL[64 * 3];                         // LOCAL nbr indices

    float4*         pc = reinterpret_cast<float4*>(smraw);          // [1024]
    unsigned short* hb = reinterpret_cast<unsigned short*>(smraw);  // [64*256]

    const int tid  = threadIdx.x;
    const int lane = tid & 63;
    const int wv   = tid >> 6;               // 0..7
    const int raw  = blockIdx.x;
    const int blk  = (raw & 7) * 128 + (raw >> 3);   // XCD-contiguous batches
    const int lo   = lane & 15;
    const int hi   = lane >> 4;
    const int b    = blk >> 6;               // 64 blocks per batch

    // ---------------- Phase K: candidate cache + top-3 scan ----------------
    #pragma unroll
    for (int k = 0; k < 2; ++k) {
        const int j = tid + k * 512;
        const float* p = pos + (size_t)(b * N_PER + j) * 3;
        float a0 = p[0], a1 = p[1], a2 = p[2];
        pc[j] = make_float4(a0, a1, a2, a0*a0 + a1*a1 + a2*a2);
    }
    __syncthreads();

    {
        const int q   = tid >> 3;            // query row 0..63
        const int sub = tid & 7;
        const int m   = blk * 64 + q;
        float nqx, nqy, nqz, qq;
        {
            const float qx = pos_skip[m*3+0], qy = pos_skip[m*3+1],
                        qz = pos_skip[m*3+2];
            qq  = qx*qx + qy*qy + qz*qz;
            nqx = -2.0f*qx; nqy = -2.0f*qy; nqz = -2.0f*qz;
        }

        float d0 = 1e30f, d1 = 1e30f, d2 = 1e30f;
        int   i0 = 0,     i1 = 0,     i2 = 0;
        #pragma unroll 4
        for (int t = 0; t < 128; ++t) {
            const int j = t*8 + sub;         // wave reads 128B bcast x8
            float4 c = pc[j];
            float r = fmaf(nqx, c.x, fmaf(nqy, c.y, fmaf(nqz, c.z, qq + c.w)));
            bool c0 = r < d0, c1 = r < d1, c2 = r < d2;
            i2 = c2 ? (c1 ? i1 : j) : i2;
            i1 = c1 ? (c0 ? i0 : j) : i1;
            i0 = c0 ? j : i0;
            d2 = c2 ? (c1 ? d1 : r) : d2;
            d1 = c1 ? (c0 ? d0 : r) : d1;
            d0 = c0 ? r : d0;
        }
        // 3-level butterfly merge across the 8 sublanes, lexicographic (d, j)
        #pragma unroll
        for (int mask = 1; mask <= 4; mask <<= 1) {
            float e0 = __shfl_xor(d0, mask), e1 = __shfl_xor(d1, mask),
                  e2 = __shfl_xor(d2, mask);
            int   j0 = __shfl_xor(i0, mask), j1 = __shfl_xor(i1, mask),
                  j2 = __shfl_xor(i2, mask);
            const float ee[3] = {e0, e1, e2};
            const int   jj[3] = {j0, j1, j2};
            #pragma unroll
            for (int s = 0; s < 3; ++s) {
                const float e = ee[s]; const int j = jj[s];
                bool c0 = (e < d0) || (e == d0 && j < i0);
                bool c1 = (e < d1) || (e == d1 && j < i1);
                bool c2 = (e < d2) || (e == d2 && j < i2);
                i2 = c2 ? (c1 ? i1 : j) : i2;
                i1 = c1 ? (c0 ? i0 : j) : i1;
                i0 = c0 ? j : i0;
                d2 = c2 ? (c1 ? d1 : e) : d2;
                d1 = c1 ? (c0 ? d0 : e) : d1;
                d0 = c0 ? e : d0;
            }
        }

        // -------- fused phase U: all 8 sublanes hold the merged top-3 -------
        if (sub < 3) {
            const int jl = (sub == 0) ? i0 : (sub == 1) ? i1 : i2;
            idxL[q*3 + sub] = jl;            // local index, for phase A

            const float qx = -0.5f*nqx, qy = -0.5f*nqy, qz = -0.5f*nqz;
            float w[3];
            const int jls[3] = {i0, i1, i2};
            #pragma unroll
            for (int s = 0; s < 3; ++s) {
                float4 c = pc[jls[s]];
                float dx = c.x - qx, dy = c.y - qy, dz = c.z - qz;
                w[s] = 1.0f / fmaxf(dx*dx + dy*dy + dz*dz, 1e-16f);
            }
            const float wsub = (sub == 0) ? w[0] : (sub == 1) ? w[1] : w[2];
            const float sS   = wsub / (w[0] + w[1] + w[2]);
            const int   nb   = b * N_PER + jl;

            float RyS[9], Rx[9];
            #pragma unroll
            for (int t = 0; t < 9; ++t) RyS[t] = sS * lframes_skip[(size_t)m*9 + t];
            #pragma unroll
            for (int t = 0; t < 9; ++t) Rx[t] = lframes[(size_t)nb*9 + t];

            float* dst = &Usc[q*28 + sub*9];
            #pragma unroll
            for (int a = 0; a < 3; ++a)
                #pragma unroll
                for (int c = 0; c < 3; ++c)
                    dst[a*3+c] = RyS[a*3+0]*Rx[c*3+0]
                               + RyS[a*3+1]*Rx[c*3+1]
                               + RyS[a*3+2]*Rx[c*3+2];
        }
    }

    // early x_skip staging for rows 32-63 (hb rows >=32 never alias pc)
    if (wv >= 4) {
        #pragma unroll
        for (int rr = 0; rr < 8; ++rr) {
            const int r = wv * 8 + rr;       // 32..63
            const int m = blk * 64 + r;
            hb[hsw(r, 192+lane)] = f2bf(x_skip[(size_t)m*FSKIP + lane]);
        }
    }
    __syncthreads();   // idxL + Usc visible; pc reads done before hb overwrite

    // ---------------- Phase A: build h (bf16), row-PAIR pipelined ----------
    for (int rr = 0; rr < 8; rr += 2) {
        const int r0 = wv * 8 + rr;
        const int r1 = r0 + 1;
        const int m0 = blk * 64 + r0;
        const int m1 = blk * 64 + r1;
        const int nbs0[3] = {b*N_PER + idxL[r0*3+0],
                             b*N_PER + idxL[r0*3+1],
                             b*N_PER + idxL[r0*3+2]};
        const int nbs1[3] = {b*N_PER + idxL[r1*3+0],
                             b*N_PER + idxL[r1*3+1],
                             b*N_PER + idxL[r1*3+2]};

        // issue ALL global gathers for both rows before any math
        float v0[3][3], v1[3][3];
        #pragma unroll
        for (int k = 0; k < 3; ++k) {
            const float* xp = x + (size_t)nbs0[k]*FDIM + lane*3;
            v0[k][0] = xp[0]; v0[k][1] = xp[1]; v0[k][2] = xp[2];
        }
        #pragma unroll
        for (int k = 0; k < 3; ++k) {
            const float* xp = x + (size_t)nbs1[k]*FDIM + lane*3;
            v1[k][0] = xp[0]; v1[k][1] = xp[1]; v1[k][2] = xp[2];
        }
        float xs0 = 0.f, xs1 = 0.f;
        if (wv < 4) {
            xs0 = x_skip[(size_t)m0*FSKIP + lane];
            xs1 = x_skip[(size_t)m1*FSKIP + lane];
        }

        // row 0: U (LDS broadcast) + FMA + write
        {
            float Ub[28];
            float4* Ub4 = reinterpret_cast<float4*>(Ub);
            #pragma unroll
            for (int t = 0; t < 7; ++t)
                Ub4[t] = *reinterpret_cast<const float4*>(&Usc[r0*28 + t*4]);
            float n0 = 0.f, n1 = 0.f, n2 = 0.f;
            #pragma unroll
            for (int k = 0; k < 3; ++k) {
                const int o = k*9;
                n0 += Ub[o+0]*v0[k][0] + Ub[o+1]*v0[k][1] + Ub[o+2]*v0[k][2];
                n1 += Ub[o+3]*v0[k][0] + Ub[o+4]*v0[k][1] + Ub[o+5]*v0[k][2];
                n2 += Ub[o+6]*v0[k][0] + Ub[o+7]*v0[k][1] + Ub[o+8]*v0[k][2];
            }
            hb[hsw(r0, lane*3+0)] = f2bf(n0);
            hb[hsw(r0, lane*3+1)] = f2bf(n1);
            hb[hsw(r0, lane*3+2)] = f2bf(n2);
            if (wv < 4) hb[hsw(r0, 192+lane)] = f2bf(xs0);
        }
        // row 1
        {
            float Ub[28];
            float4* Ub4 = reinterpret_cast<float4*>(Ub);
            #pragma unroll
            for (int t = 0; t < 7; ++t)
                Ub4[t] = *reinterpret_cast<const float4*>(&Usc[r1*28 + t*4]);
            float n0 = 0.f, n1 = 0.f, n2 = 0.f;
            #pragma unroll
            for (int k = 0; k < 3; ++k) {
                const int o = k*9;
                n0 += Ub[o+0]*v1[k][0] + Ub[o+1]*v1[k][1] + Ub[o+2]*v1[k][2];
                n1 += Ub[o+3]*v1[k][0] + Ub[o+4]*v1[k][1] + Ub[o+5]*v1[k][2];
                n2 += Ub[o+6]*v1[k][0] + Ub[o+7]*v1[k][1] + Ub[o+8]*v1[k][2];
            }
            hb[hsw(r1, lane*3+0)] = f2bf(n0);
            hb[hsw(r1, lane*3+1)] = f2bf(n1);
            hb[hsw(r1, lane*3+2)] = f2bf(n2);
            if (wv < 4) hb[hsw(r1, 192+lane)] = f2bf(xs1);
        }
    }
    __syncthreads();

    // ---------------- GEMM1: hidden = relu(h @ W1 + b1) ----------------
    // wave wv covers cols [wv*32, wv*32+32); B-frags prefetched 1 K-step ahead
    f32x4 acc[4][2];
    #pragma unroll
    for (int fi = 0; fi < 4; ++fi)
        #pragma unroll
        for (int ci = 0; ci < 2; ++ci) acc[fi][ci] = (f32x4)0.f;

    short8v bfn[2];
    #pragma unroll
    for (int ci = 0; ci < 2; ++ci)
        bfn[ci] = *reinterpret_cast<const short8v*>(
            &wt1[(wv*32 + ci*16 + lo)*256 + hi*8]);

    for (int ks = 0; ks < 8; ++ks) {
        const int kk = ks*32 + hi*8;
        short8v bf0 = bfn[0], bf1 = bfn[1];
        if (ks < 7) {
            #pragma unroll
            for (int ci = 0; ci < 2; ++ci)
                bfn[ci] = *reinterpret_cast<const short8v*>(
                    &wt1[(wv*32 + ci*16 + lo)*256 + kk + 32]);
        }
        short8v a[4];
        #pragma unroll
        for (int fi = 0; fi < 4; ++fi) {
            const int r = fi*16 + lo;
            a[fi] = *reinterpret_cast<const short8v*>(
                &hb[r*256 + (kk ^ ((lo & 7) << 3))]);
        }
        #pragma unroll
        for (int fi = 0; fi < 4; ++fi) {
            acc[fi][0] = __builtin_amdgcn_mfma_f32_16x16x32_bf16(
                a[fi], bf0, acc[fi][0], 0, 0, 0);
            acc[fi][1] = __builtin_amdgcn_mfma_f32_16x16x32_bf16(
                a[fi], bf1, acc[fi][1], 0, 0, 0);
        }
    }
    __syncthreads();   // all GEMM1 reads of h complete

    {
        float b1v[2];
        #pragma unroll
        for (int ci = 0; ci < 2; ++ci) b1v[ci] = b1[wv*32 + ci*16 + lo];
        #pragma unroll
        for (int fi = 0; fi < 4; ++fi)
            #pragma unroll
            for (int ci = 0; ci < 2; ++ci)
                #pragma unroll
                for (int q = 0; q < 4; ++q) {
                    const int r = fi*16 + hi*4 + q;
                    const int c = wv*32 + ci*16 + lo;
                    hb[hsw(r, c)] = f2bf(fmaxf(acc[fi][ci][q] + b1v[ci], 0.f));
                }
    }
    __syncthreads();

    // ---------------- GEMM2: out = hidden @ W2 + b2 ----------------
    // wave wv covers cols [wv*16, wv*16+16); B-frag prefetched 1 K-step ahead
    f32x4 acc2[4];
    #pragma unroll
    for (int fi = 0; fi < 4; ++fi) acc2[fi] = (f32x4)0.f;

    short8v bf2n = *reinterpret_cast<const short8v*>(
        &wt2[(wv*16 + lo)*256 + hi*8]);

    for (int ks = 0; ks < 8; ++ks) {
        const int kk = ks*32 + hi*8;
        short8v bf = bf2n;
        if (ks < 7)
            bf2n = *reinterpret_cast<const short8v*>(
                &wt2[(wv*16 + lo)*256 + kk + 32]);
        short8v a[4];
        #pragma unroll
        for (int fi = 0; fi < 4; ++fi) {
            const int r = fi*16 + lo;
            a[fi] = *reinterpret_cast<const short8v*>(
                &hb[r*256 + (kk ^ ((lo & 7) << 3))]);
        }
        #pragma unroll
        for (int fi = 0; fi < 4; ++fi)
            acc2[fi] = __builtin_amdgcn_mfma_f32_16x16x32_bf16(
                a[fi], bf, acc2[fi], 0, 0, 0);
    }

    {
        const float b2v = b2[wv*16 + lo];
        #pragma unroll
        for (int fi = 0; fi < 4; ++fi)
            #pragma unroll
            for (int q = 0; q < 4; ++q) {
                const int r = fi*16 + hi*4 + q;
                const int c = wv*16 + lo;
                out[(size_t)(blk*64 + r)*ODIM + c] = acc2[fi][q] + b2v;
            }
    }
}

extern "C" void kernel_launch(void* const* d_in, const int* in_sizes, int n_in,
                              void* d_out, int out_size, void* d_ws, size_t ws_size,
                              hipStream_t stream) {
    const float* x            = (const float*)d_in[0];
    const float* pos          = (const float*)d_in[1];
    const float* pos_skip     = (const float*)d_in[2];
    const float* x_skip       = (const float*)d_in[3];
    const float* lframes      = (const float*)d_in[4];
    const float* lframes_skip = (const float*)d_in[5];
    const float* W1           = (const float*)d_in[6];
    const float* b1           = (const float*)d_in[7];
    const float* W2           = (const float*)d_in[8];
    const float* b2           = (const float*)d_in[9];
    const int*   batch_skip   = (const int*)d_in[11];

    char* ws = (char*)d_ws;
    unsigned short* wt1 = (unsigned short*)ws;                 // 131072 B
    unsigned short* wt2 = (unsigned short*)(ws + 131072);      // 65536 B
    float* out  = (float*)d_out;
    float* tail = out + (size_t)M_TOT * ODIM;

    // merged prep + tail: 950272 threads = 3712 blocks
    prep_tail_kernel<<<3712, 256, 0, stream>>>(W1, W2, pos_skip, batch_skip,
                                               lframes_skip, wt1, wt2, tail);

    fused_kernel<<<M_TOT/64, 512, 0, stream>>>(x, pos, pos_skip, x_skip,
                                               lframes, lframes_skip,
                                               wt1, b1, wt2, b2, out);
}